// Round 2
// baseline (282.615 us; speedup 1.0000x reference)
//
#include <hip/hip_runtime.h>
#include <math.h>

#define N_TOT 4194304  // 64*256*256

__device__ __forceinline__ float sgnf(float x) {
    return x > 0.f ? 1.f : (x < 0.f ? -1.f : 0.f);
}

__device__ __forceinline__ float gelu_f(float v) {
    // jax.nn.gelu approximate=True (tanh form)
    const float c0 = 0.7978845608028654f;
    float inner = c0 * fmaf(0.044715f * v, v * v, v);
    return 0.5f * v * (1.f + tanhf(inner));
}

// ---------------------------------------------------------------------------
// Kernel A: per-channel Hopfield fixed-point -> alpha[c] = bp_c . v5
// 64 blocks (one per channel) x 64 threads (one per d)
// ---------------------------------------------------------------------------
__global__ __launch_bounds__(64) void alpha_kernel(const float* __restrict__ bp,
                                                   const float* __restrict__ Wm,
                                                   float* __restrict__ alpha) {
    const int c = blockIdx.x, d = threadIdx.x;
    __shared__ float v[64];
    float bpv = bp[c * 64 + d];
    v[d] = sgnf(bpv);
    __syncthreads();
    const float* row = Wm + c * 4096 + d * 64;
    for (int it = 0; it < 5; ++it) {
        float s = 0.f;
        #pragma unroll
        for (int e = 0; e < 64; ++e) s = fmaf(row[e], v[e], s);
        __syncthreads();
        v[d] = sgnf(s);
        __syncthreads();
    }
    float val = bpv * v[d];
    #pragma unroll
    for (int off = 32; off; off >>= 1) val += __shfl_down(val, off);
    if (d == 0) alpha[c] = val;
}

// ---------------------------------------------------------------------------
// Kernel B: 3x3 SAME conv (fp32) + bias, fused y = q + sgn(q)*alpha[c],
// writes y into d_out, emits per-block double partial sums (sum, sumsq).
// Grid: 16x16 pixel tiles (256 tiles) x 2 co-halves = 512 blocks, 256 thr.
// ---------------------------------------------------------------------------
__global__ __launch_bounds__(256) void conv_kernel(const float* __restrict__ x,
                                                   const float* __restrict__ cw,
                                                   const float* __restrict__ cb,
                                                   const float* __restrict__ alpha,
                                                   float* __restrict__ y,
                                                   double* __restrict__ partials) {
    const int tid = threadIdx.x;
    const int b = blockIdx.x;
    const int bx = b & 15;
    const int by = (b >> 4) & 15;
    const int co_base = (b >> 8) * 32;
    const int lx = tid & 15, ly = tid >> 4;
    const int gx = (bx << 4) + lx, gy = (by << 4) + ly;
    const int x0 = (bx << 4) - 1, y0 = (by << 4) - 1;

    __shared__ float xs[8][18][18];
    __shared__ double red[4][2];

    float acc[32];
    #pragma unroll
    for (int i = 0; i < 32; i++) acc[i] = cb[co_base + i];

    for (int ci0 = 0; ci0 < 64; ci0 += 8) {
        __syncthreads();
        for (int idx = tid; idx < 2592; idx += 256) {
            int ci = idx / 324;
            int rem = idx - ci * 324;
            int r = rem / 18;
            int c = rem - r * 18;
            int yy = y0 + r, xx = x0 + c;
            float v = 0.f;
            if (((unsigned)yy < 256u) && ((unsigned)xx < 256u))
                v = x[((ci0 + ci) << 16) + (yy << 8) + xx];
            xs[ci][r][c] = v;
        }
        __syncthreads();
        #pragma unroll
        for (int ci = 0; ci < 8; ++ci) {
            const float x00 = xs[ci][ly    ][lx], x01 = xs[ci][ly    ][lx + 1], x02 = xs[ci][ly    ][lx + 2];
            const float x10 = xs[ci][ly + 1][lx], x11 = xs[ci][ly + 1][lx + 1], x12 = xs[ci][ly + 1][lx + 2];
            const float x20 = xs[ci][ly + 2][lx], x21 = xs[ci][ly + 2][lx + 1], x22 = xs[ci][ly + 2][lx + 2];
            const float* wp = cw + co_base * 576 + (ci0 + ci) * 9;
            #pragma unroll
            for (int co = 0; co < 32; ++co) {
                const float* w = wp + co * 576;
                float a = acc[co];
                a = fmaf(w[0], x00, a); a = fmaf(w[1], x01, a); a = fmaf(w[2], x02, a);
                a = fmaf(w[3], x10, a); a = fmaf(w[4], x11, a); a = fmaf(w[5], x12, a);
                a = fmaf(w[6], x20, a); a = fmaf(w[7], x21, a); a = fmaf(w[8], x22, a);
                acc[co] = a;
            }
        }
    }

    double s1 = 0.0, s2 = 0.0;
    const int opix = (gy << 8) + gx;
    #pragma unroll
    for (int co = 0; co < 32; ++co) {
        float q = acc[co];
        float a = alpha[co_base + co];
        float yv = q + (q > 0.f ? a : (q < 0.f ? -a : 0.f));
        y[((co_base + co) << 16) + opix] = yv;
        s1 += (double)yv;
        s2 += (double)yv * (double)yv;
    }
    #pragma unroll
    for (int off = 32; off; off >>= 1) {
        s1 += __shfl_down(s1, off);
        s2 += __shfl_down(s2, off);
    }
    const int wid = tid >> 6;
    if ((tid & 63) == 0) { red[wid][0] = s1; red[wid][1] = s2; }
    __syncthreads();
    if (tid == 0) {
        double a1 = red[0][0] + red[1][0] + red[2][0] + red[3][0];
        double a2 = red[0][1] + red[1][1] + red[2][1] + red[3][1];
        partials[blockIdx.x * 2]     = a1;
        partials[blockIdx.x * 2 + 1] = a2;
    }
}

// ---------------------------------------------------------------------------
// Kernel C: reduce 512 partial pairs -> mean, inv_std (deterministic)
// ---------------------------------------------------------------------------
__global__ __launch_bounds__(256) void stats_kernel(const double* __restrict__ partials,
                                                    float* __restrict__ stats) {
    const int tid = threadIdx.x;
    double s1 = 0.0, s2 = 0.0;
    for (int i = tid; i < 512; i += 256) {
        s1 += partials[2 * i];
        s2 += partials[2 * i + 1];
    }
    #pragma unroll
    for (int off = 32; off; off >>= 1) {
        s1 += __shfl_down(s1, off);
        s2 += __shfl_down(s2, off);
    }
    __shared__ double red[4][2];
    const int wid = tid >> 6;
    if ((tid & 63) == 0) { red[wid][0] = s1; red[wid][1] = s2; }
    __syncthreads();
    if (tid == 0) {
        double a1 = red[0][0] + red[1][0] + red[2][0] + red[3][0];
        double a2 = red[0][1] + red[1][1] + red[2][1] + red[3][1];
        double mean = a1 / (double)N_TOT;
        double var = a2 / (double)N_TOT - mean * mean;
        stats[0] = (float)mean;
        stats[1] = (float)(1.0 / sqrt(var + 1e-5));
    }
}

// ---------------------------------------------------------------------------
// Kernel D: in-place (y in d_out) groupnorm-affine + gelu, float4 vectorized
// ---------------------------------------------------------------------------
__global__ __launch_bounds__(256) void finalize_kernel(float* __restrict__ y,
                                                       const float* __restrict__ stats,
                                                       const float* __restrict__ gnw,
                                                       const float* __restrict__ gnb) {
    const int i = blockIdx.x * 256 + threadIdx.x;  // float4 index, 1048576 total
    const float mean = stats[0], istd = stats[1];
    const int c = i >> 14;  // 16384 float4 per channel
    const float scale = gnw[c] * istd;
    const float shift = gnb[c] - mean * scale;
    float4 v = reinterpret_cast<float4*>(y)[i];
    v.x = gelu_f(fmaf(v.x, scale, shift));
    v.y = gelu_f(fmaf(v.y, scale, shift));
    v.z = gelu_f(fmaf(v.z, scale, shift));
    v.w = gelu_f(fmaf(v.w, scale, shift));
    reinterpret_cast<float4*>(y)[i] = v;
}

extern "C" void kernel_launch(void* const* d_in, const int* in_sizes, int n_in,
                              void* d_out, int out_size, void* d_ws, size_t ws_size,
                              hipStream_t stream) {
    const float* x   = (const float*)d_in[0];
    const float* cw  = (const float*)d_in[1];
    const float* cb  = (const float*)d_in[2];
    const float* bp  = (const float*)d_in[3];
    const float* Wm  = (const float*)d_in[4];
    const float* gnw = (const float*)d_in[5];
    const float* gnb = (const float*)d_in[6];
    float* out = (float*)d_out;

    char* ws = (char*)d_ws;
    float* alpha     = (float*)ws;            // 64 floats
    float* stats     = (float*)(ws + 256);    // 2 floats
    double* partials = (double*)(ws + 512);   // 512*2 doubles

    alpha_kernel<<<64, 64, 0, stream>>>(bp, Wm, alpha);
    conv_kernel<<<512, 256, 0, stream>>>(x, cw, cb, alpha, out, partials);
    stats_kernel<<<1, 256, 0, stream>>>(partials, stats);
    finalize_kernel<<<4096, 256, 0, stream>>>(out, stats, gnw, gnb);
}

// Round 3
// 160.923 us; speedup vs baseline: 1.7562x; 1.7562x over previous
//
#include <hip/hip_runtime.h>
#include <math.h>

#define N_TOT 4194304  // 64*256*256
#define NBLK 2048      // conv grid: 256 tiles x 8 co-groups

__device__ __forceinline__ float sgnf(float x) {
    return x > 0.f ? 1.f : (x < 0.f ? -1.f : 0.f);
}

__device__ __forceinline__ float gelu_f(float v) {
    // jax.nn.gelu approximate=True (tanh form)
    const float c0 = 0.7978845608028654f;
    float inner = c0 * fmaf(0.044715f * v, v * v, v);
    return 0.5f * v * (1.f + tanhf(inner));
}

// ---------------------------------------------------------------------------
// Kernel A: per-channel Hopfield fixed-point -> alpha[c] = bp_c . v5
// sign(q*bp) factors; sign(W@(s*v)) = s*sign(W@v) for s=+-1, so the 5-iter
// recurrence is pixel-independent: v <- sign(W_c v), v0 = sign(bp_c).
// ---------------------------------------------------------------------------
__global__ __launch_bounds__(64) void alpha_kernel(const float* __restrict__ bp,
                                                   const float* __restrict__ Wm,
                                                   float* __restrict__ alpha) {
    const int c = blockIdx.x, d = threadIdx.x;
    __shared__ float v[64];
    float bpv = bp[c * 64 + d];
    v[d] = sgnf(bpv);
    __syncthreads();
    const float* row = Wm + c * 4096 + d * 64;
    for (int it = 0; it < 5; ++it) {
        float s = 0.f;
        #pragma unroll
        for (int e = 0; e < 64; ++e) s = fmaf(row[e], v[e], s);
        __syncthreads();
        v[d] = sgnf(s);
        __syncthreads();
    }
    float val = bpv * v[d];
    #pragma unroll
    for (int off = 32; off; off >>= 1) val += __shfl_down(val, off);
    if (d == 0) alpha[c] = val;
}

// ---------------------------------------------------------------------------
// Kernel B: 3x3 SAME conv (fp32) + bias, fused y = q + sgn(q)*alpha[c],
// per-block double partial sums. Grid: 256 tiles x 8 co-groups = 2048 blocks.
// xs layout [r][ci][c]: row stride 144 dwords == 16 mod 32 -> each wave's
// 4 rows x 16 cols cover every bank exactly 2x (conflict-free).
// ---------------------------------------------------------------------------
__global__ __launch_bounds__(256, 8) void conv_kernel(const float* __restrict__ x,
                                                      const float* __restrict__ cw,
                                                      const float* __restrict__ cb,
                                                      const float* __restrict__ alpha,
                                                      float* __restrict__ y,
                                                      double* __restrict__ partials) {
    const int tid = threadIdx.x;
    const int b = blockIdx.x;
    const int bx = b & 15;
    const int by = (b >> 4) & 15;
    const int co_base = (b >> 8) * 8;
    const int lx = tid & 15, ly = tid >> 4;
    const int gx = (bx << 4) + lx, gy = (by << 4) + ly;
    const int x0 = (bx << 4) - 1, y0 = (by << 4) - 1;

    __shared__ float xs[18][8][18];  // [r][ci][c]
    __shared__ double red[4][2];

    float acc[8];
    #pragma unroll
    for (int i = 0; i < 8; i++) acc[i] = cb[co_base + i];

    for (int ci0 = 0; ci0 < 64; ci0 += 8) {
        __syncthreads();
        for (int idx = tid; idx < 2592; idx += 256) {
            int r = idx / 144;              // flat addr == idx (stride match)
            int rem = idx - r * 144;
            int ci = rem / 18;
            int c = rem - ci * 18;
            int yy = y0 + r, xx = x0 + c;
            float v = 0.f;
            if (((unsigned)yy < 256u) && ((unsigned)xx < 256u))
                v = x[((ci0 + ci) << 16) + (yy << 8) + xx];
            xs[r][ci][c] = v;
        }
        __syncthreads();
        #pragma unroll
        for (int ci = 0; ci < 8; ++ci) {
            const float x00 = xs[ly    ][ci][lx], x01 = xs[ly    ][ci][lx + 1], x02 = xs[ly    ][ci][lx + 2];
            const float x10 = xs[ly + 1][ci][lx], x11 = xs[ly + 1][ci][lx + 1], x12 = xs[ly + 1][ci][lx + 2];
            const float x20 = xs[ly + 2][ci][lx], x21 = xs[ly + 2][ci][lx + 1], x22 = xs[ly + 2][ci][lx + 2];
            const float* wp = cw + co_base * 576 + (ci0 + ci) * 9;
            #pragma unroll
            for (int co = 0; co < 8; ++co) {
                const float* w = wp + co * 576;
                float a = acc[co];
                a = fmaf(w[0], x00, a); a = fmaf(w[1], x01, a); a = fmaf(w[2], x02, a);
                a = fmaf(w[3], x10, a); a = fmaf(w[4], x11, a); a = fmaf(w[5], x12, a);
                a = fmaf(w[6], x20, a); a = fmaf(w[7], x21, a); a = fmaf(w[8], x22, a);
                acc[co] = a;
            }
        }
    }

    double s1 = 0.0, s2 = 0.0;
    const int opix = (gy << 8) + gx;
    #pragma unroll
    for (int co = 0; co < 8; ++co) {
        float q = acc[co];
        float a = alpha[co_base + co];
        float yv = q + (q > 0.f ? a : (q < 0.f ? -a : 0.f));
        y[((co_base + co) << 16) + opix] = yv;
        s1 += (double)yv;
        s2 += (double)yv * (double)yv;
    }
    #pragma unroll
    for (int off = 32; off; off >>= 1) {
        s1 += __shfl_down(s1, off);
        s2 += __shfl_down(s2, off);
    }
    const int wid = tid >> 6;
    if ((tid & 63) == 0) { red[wid][0] = s1; red[wid][1] = s2; }
    __syncthreads();
    if (tid == 0) {
        double a1 = red[0][0] + red[1][0] + red[2][0] + red[3][0];
        double a2 = red[0][1] + red[1][1] + red[2][1] + red[3][1];
        partials[blockIdx.x * 2]     = a1;
        partials[blockIdx.x * 2 + 1] = a2;
    }
}

// ---------------------------------------------------------------------------
// Kernel C: reduce NBLK partial pairs -> mean, inv_std (deterministic)
// ---------------------------------------------------------------------------
__global__ __launch_bounds__(256) void stats_kernel(const double* __restrict__ partials,
                                                    float* __restrict__ stats) {
    const int tid = threadIdx.x;
    double s1 = 0.0, s2 = 0.0;
    for (int i = tid; i < NBLK; i += 256) {
        s1 += partials[2 * i];
        s2 += partials[2 * i + 1];
    }
    #pragma unroll
    for (int off = 32; off; off >>= 1) {
        s1 += __shfl_down(s1, off);
        s2 += __shfl_down(s2, off);
    }
    __shared__ double red[4][2];
    const int wid = tid >> 6;
    if ((tid & 63) == 0) { red[wid][0] = s1; red[wid][1] = s2; }
    __syncthreads();
    if (tid == 0) {
        double a1 = red[0][0] + red[1][0] + red[2][0] + red[3][0];
        double a2 = red[0][1] + red[1][1] + red[2][1] + red[3][1];
        double mean = a1 / (double)N_TOT;
        double var = a2 / (double)N_TOT - mean * mean;
        stats[0] = (float)mean;
        stats[1] = (float)(1.0 / sqrt(var + 1e-5));
    }
}

// ---------------------------------------------------------------------------
// Kernel D: in-place (y in d_out) norm-affine + gelu, float4 vectorized
// ---------------------------------------------------------------------------
__global__ __launch_bounds__(256) void finalize_kernel(float* __restrict__ y,
                                                       const float* __restrict__ stats,
                                                       const float* __restrict__ gnw,
                                                       const float* __restrict__ gnb) {
    const int i = blockIdx.x * 256 + threadIdx.x;  // float4 index, 1048576 total
    const float mean = stats[0], istd = stats[1];
    const int c = i >> 14;  // 16384 float4 per channel
    const float scale = gnw[c] * istd;
    const float shift = gnb[c] - mean * scale;
    float4 v = reinterpret_cast<float4*>(y)[i];
    v.x = gelu_f(fmaf(v.x, scale, shift));
    v.y = gelu_f(fmaf(v.y, scale, shift));
    v.z = gelu_f(fmaf(v.z, scale, shift));
    v.w = gelu_f(fmaf(v.w, scale, shift));
    reinterpret_cast<float4*>(y)[i] = v;
}

extern "C" void kernel_launch(void* const* d_in, const int* in_sizes, int n_in,
                              void* d_out, int out_size, void* d_ws, size_t ws_size,
                              hipStream_t stream) {
    const float* x   = (const float*)d_in[0];
    const float* cw  = (const float*)d_in[1];
    const float* cb  = (const float*)d_in[2];
    const float* bp  = (const float*)d_in[3];
    const float* Wm  = (const float*)d_in[4];
    const float* gnw = (const float*)d_in[5];
    const float* gnb = (const float*)d_in[6];
    float* out = (float*)d_out;

    char* ws = (char*)d_ws;
    float* alpha     = (float*)ws;            // 64 floats
    float* stats     = (float*)(ws + 256);    // 2 floats
    double* partials = (double*)(ws + 512);   // NBLK*2 doubles

    alpha_kernel<<<64, 64, 0, stream>>>(bp, Wm, alpha);
    conv_kernel<<<NBLK, 256, 0, stream>>>(x, cw, cb, alpha, out, partials);
    stats_kernel<<<1, 256, 0, stream>>>(partials, stats);
    finalize_kernel<<<4096, 256, 0, stream>>>(out, stats, gnw, gnb);
}